// Round 10
// baseline (412.249 us; speedup 1.0000x reference)
//
#include <hip/hip_runtime.h>
#include <hip/hip_bf16.h>
#include <stdint.h>

typedef float f32x4 __attribute__((ext_vector_type(4)));
typedef __bf16 bf16x8 __attribute__((ext_vector_type(8)));

#define MFMA16(a,b,c) __builtin_amdgcn_mfma_f32_16x16x32_bf16((a),(b),(c),0,0,0)

// Shapes
#define NSEQ 256
#define NRES 384
#define CM   256
#define CH   32
#define CZ   128

// workspace offsets (bytes)
#define WS_AT    0ull                 // 12288*256 bf16 = 6291456
#define WS_BT    6291456ull           // 6291456
#define WS_WOT   12582912ull          // 128*1024 bf16 = 262144
#define WS_WPACK 12845056ull          // 64*256 bf16 = 32768
#define WS_BPACK 12877824ull          // 64 f32 = 256
#define WS_NORM  12878080ull          // 384*384 f32 = 589824

static __device__ __forceinline__ void gload_lds16(const void* g, void* l) {
  __builtin_amdgcn_global_load_lds(
      (const __attribute__((address_space(1))) void*)g,
      (__attribute__((address_space(3))) void*)l, 16, 0, 0);
}

static __device__ __forceinline__ unsigned pack2bf(float a, float b) {
  unsigned short ha = __builtin_bit_cast(unsigned short, (__bf16)a);
  unsigned short hb = __builtin_bit_cast(unsigned short, (__bf16)b);
  return (unsigned)ha | ((unsigned)hb << 16);
}

// ---------------- merged prep kernel ----------------
// grid 960 x 256 thr:
//  blocks [0,64):    fold LN affine into wpack/bpack (c = bid)
//  blocks [64,576):  wo transpose -> wo_t[z][e*32+c]
//  blocks [576,960): norm[i][j] = sum_s mask[s][i]*mask[s][j] (i = bid-576)
__global__ void __launch_bounds__(256)
k_prep(const float* __restrict__ ln_w, const float* __restrict__ ln_b,
       const float* __restrict__ w1, const float* __restrict__ b1,
       const float* __restrict__ w2, const float* __restrict__ b2,
       const float* __restrict__ wo, const float* __restrict__ mask,
       __bf16* __restrict__ wpack, float* __restrict__ bpack,
       __bf16* __restrict__ wo_t, float* __restrict__ norm) {
  const int bid = blockIdx.x, tid = threadIdx.x;
  if (bid < 64) {
    // wpack[c][k] = ln_w[k]*w{1,2}[k][c&31]; bpack[c] = b[c&31] + sum_k ln_b[k]*w[k][c&31]
    __shared__ float red[4];
    int c = bid, k = tid, col = c & 31;
    const float* w  = (c >= 32) ? w2 : w1;
    const float* bb = (c >= 32) ? b2 : b1;
    float wv = w[k * CH + col];
    wpack[c * CM + k] = (__bf16)(ln_w[k] * wv);
    float t = ln_b[k] * wv;
#pragma unroll
    for (int d = 32; d > 0; d >>= 1) t += __shfl_xor(t, d);
    if ((k & 63) == 0) red[k >> 6] = t;
    __syncthreads();
    if (k == 0) bpack[c] = bb[col] + red[0] + red[1] + red[2] + red[3];
  } else if (bid < 576) {
    // wo_t[z][e*32+c] = bf16(wo[(c*32+e)*128 + z]); coalesced reads
    int tg = (bid - 64) * 256 + tid;   // 0..131071
    int r = tg >> 7;                   // wo row = c*32+e
    int z = tg & 127;
    int c = r >> 5, e = r & 31;
    wo_t[(size_t)z * 1024 + e * 32 + c] = (__bf16)wo[(size_t)r * CZ + z];
  } else {
    int i = bid - 576;
    for (int j = tid; j < NRES; j += 256) {
      float acc = 0.f;
      for (int s = 0; s < NSEQ; ++s)
        acc += mask[s * NRES + i] * mask[s * NRES + j];
      norm[i * NRES + j] = acc;
    }
  }
}

// ---------------- fused LN + projection ----------------
// block: 256 thr (4 waves). grid 1536: i = bid>>2, sblk = bid&3 (64 s each).
// wave w handles 16 s rows; MFMA 16x16x32 over K=256 against wpack (64 cols).
// outputs: a_t[i*32+c][s], b_t[i*32+e][s]  (bf16, K(=s)-contiguous rows)
__global__ void __launch_bounds__(256)
k_lnproj(const float* __restrict__ mm, const float* __restrict__ mask,
         const __bf16* __restrict__ wpack, const float* __restrict__ bpack,
         __bf16* __restrict__ a_t, __bf16* __restrict__ b_t) {
  __shared__ __align__(16) unsigned char sw[32768];  // wpack swizzled [64][512B]
  __shared__ float stg[64 * 68];                     // out stage [64 s][64+pad cols]

  const int tid = threadIdx.x;
  const int bid = blockIdx.x;
  const int i = bid >> 2, sblk = bid & 3;
  const int wid = tid >> 6, lane = tid & 63, l15 = lane & 15, g = lane >> 4;

  // stage wpack -> LDS with XOR swizzle (row=col, 512B rows)
#pragma unroll
  for (int it = 0; it < 8; ++it) {
    int idx = it * 256 + tid;        // 16B chunk id 0..2047
    int col = idx >> 5;
    int cb = (idx & 31) * 16;
    uint4 v = *(const uint4*)((const char*)wpack + (size_t)idx * 16);
    *(uint4*)(&sw[col * 512 + (cb ^ ((col & 7) << 4))]) = v;
  }
  __syncthreads();

  const int s_row = sblk * 64 + wid * 16 + l15;
  const char* rowp = (const char*)mm + (size_t)(s_row * NRES + i) * (CM * 4);

  // load x: lane holds k = kc*32 + g*8 + j  (kc=0..7, j=0..7)
  float xv[8][8];
#pragma unroll
  for (int kc = 0; kc < 8; ++kc) {
    f32x4 v0 = *(const f32x4*)(rowp + kc * 128 + g * 32);
    f32x4 v1 = *(const f32x4*)(rowp + kc * 128 + g * 32 + 16);
#pragma unroll
    for (int j = 0; j < 4; ++j) { xv[kc][j] = v0[j]; xv[kc][4 + j] = v1[j]; }
  }
  // LN stats (row spread over lanes l, l^16, l^32, l^48)
  float s1 = 0.f, s2 = 0.f;
#pragma unroll
  for (int kc = 0; kc < 8; ++kc)
#pragma unroll
    for (int j = 0; j < 8; ++j) { float t = xv[kc][j]; s1 += t; s2 += t * t; }
  s1 += __shfl_xor(s1, 16); s1 += __shfl_xor(s1, 32);
  s2 += __shfl_xor(s2, 16); s2 += __shfl_xor(s2, 32);
  float mu = s1 * (1.f / 256.f);
  float var = s2 * (1.f / 256.f) - mu * mu;
  float mk = mask[s_row * NRES + i];
  float scl = rsqrtf(var + 1e-5f) * mk;   // fold mask into x (A-rows are l15-indexed)

  f32x4 zero4 = {0.f, 0.f, 0.f, 0.f};
  f32x4 acc[4] = {zero4, zero4, zero4, zero4};
#pragma unroll
  for (int kc = 0; kc < 8; ++kc) {
    bf16x8 af;
#pragma unroll
    for (int j = 0; j < 8; ++j) af[j] = (__bf16)((xv[kc][j] - mu) * scl);
#pragma unroll
    for (int ct = 0; ct < 4; ++ct) {
      int col = ct * 16 + l15;
      bf16x8 bf = *(const bf16x8*)(&sw[col * 512 + ((kc * 64 + g * 16) ^ ((col & 7) << 4))]);
      acc[ct] = MFMA16(af, bf, acc[ct]);
    }
  }
  // epilogue: += mask*bpack, stage to LDS  (D row = g*4+j, col = ct*16+l15)
  float mks[4];
#pragma unroll
  for (int j = 0; j < 4; ++j)
    mks[j] = mask[(sblk * 64 + wid * 16 + g * 4 + j) * NRES + i];
#pragma unroll
  for (int ct = 0; ct < 4; ++ct) {
    int col = ct * 16 + l15;
    float bp = bpack[col];
#pragma unroll
    for (int j = 0; j < 4; ++j)
      stg[(wid * 16 + g * 4 + j) * 68 + col] = acc[ct][j] + mks[j] * bp;
  }
  __syncthreads();

  // pack-out transposed: thread t -> col = t>>2, s-quarter = t&3 (16 s, 32B)
  int col = tid >> 2, sq = tid & 3;
  unsigned pk[8];
#pragma unroll
  for (int p = 0; p < 8; ++p) {
    float v0 = stg[(sq * 16 + p * 2) * 68 + col];
    float v1 = stg[(sq * 16 + p * 2 + 1) * 68 + col];
    pk[p] = pack2bf(v0, v1);
  }
  char* db = (char*)((col < 32) ? (a_t + (size_t)(i * 32 + col) * NSEQ)
                                : (b_t + (size_t)(i * 32 + col - 32) * NSEQ))
             + (sblk * 64 + sq * 16) * 2;
  uint4 u0; u0.x = pk[0]; u0.y = pk[1]; u0.z = pk[2]; u0.w = pk[3];
  uint4 u1; u1.x = pk[4]; u1.y = pk[5]; u1.z = pk[6]; u1.w = pk[7];
  *(uint4*)db = u0;
  *(uint4*)(db + 16) = u1;
}

// ---------------- main fused kernel ----------------
// grid 4608 = 48(bi: 8 i's) x 96(bj: 4 j's). 512 thr (8 waves, 4x2).
// __launch_bounds__(512,4): cap VGPR<=128 so 2 blocks/CU co-reside ->
// one block's phase A (MFMA-bound) overlaps another's phase B (L2-bound).
// Phase A: C1[m=il*32+c][n=jl*32+e] = sum_s a_t[bi*256+m][s]*b_t[bj*128+n][s]
//          (M=256,N=128,K=256; BK=64 single-buffered LDS, XOR swizzle)
// C1 -> LDS bf16 [32 pairs][1024 (e*32+c)] (64KB, overlaps A/B tiles)
// Phase B: out[pair][z] = sum_k C1[pair][k]*wo_t[z][k]; +bo, /(eps+norm)
__global__ void __launch_bounds__(512, 4)
k_main(const __bf16* __restrict__ a_t, const __bf16* __restrict__ b_t,
       const __bf16* __restrict__ wo_t, const float* __restrict__ bo,
       const float* __restrict__ norm, float* __restrict__ out) {
  __shared__ __align__(16) unsigned char smem[65536];
  const int ABASE = 0, BBASE = 32768;

  const int tid = threadIdx.x;
  const int wid = tid >> 6, lane = tid & 63, l15 = lane & 15, g = lane >> 4;
  const int bid = blockIdx.x;
  const int bi = bid / 96, bj = bid % 96;
  const int wm = wid >> 1, wn = wid & 1;

  const char* abase = (const char*)a_t + (size_t)bi * 256 * 512;
  const char* bbase = (const char*)b_t + (size_t)bj * 128 * 512;

  f32x4 zero4 = {0.f, 0.f, 0.f, 0.f};
  f32x4 acc[4][4];
#pragma unroll
  for (int mt = 0; mt < 4; ++mt)
#pragma unroll
    for (int nt = 0; nt < 4; ++nt) acc[mt][nt] = zero4;

  for (int q = 0; q < 4; ++q) {   // K chunks of 64
    __syncthreads();
    // stage A rows [wid*32,+32), B rows [wid*16,+16); 128B per row-chunk
#pragma unroll
    for (int it = 0; it < 4; ++it) {
      int r = wid * 32 + it * 8 + (lane >> 3);
      int cb = (lane & 7) * 16;
      gload_lds16(abase + (size_t)r * 512 + q * 128 + (cb ^ ((r & 7) << 4)),
                  &smem[ABASE + (wid * 32 + it * 8) * 128]);
    }
#pragma unroll
    for (int it = 0; it < 2; ++it) {
      int r = wid * 16 + it * 8 + (lane >> 3);
      int cb = (lane & 7) * 16;
      gload_lds16(bbase + (size_t)r * 512 + q * 128 + (cb ^ ((r & 7) << 4)),
                  &smem[BBASE + (wid * 16 + it * 8) * 128]);
    }
    __syncthreads();
#pragma unroll
    for (int kc = 0; kc < 2; ++kc) {
      bf16x8 af[4];
#pragma unroll
      for (int mt = 0; mt < 4; ++mt) {
        int row = wm * 64 + mt * 16 + l15;
        af[mt] = *(const bf16x8*)(&smem[ABASE + row * 128 + ((kc * 64 + g * 16) ^ ((row & 7) << 4))]);
      }
#pragma unroll
      for (int nt = 0; nt < 4; ++nt) {
        int row = wn * 64 + nt * 16 + l15;
        bf16x8 bf = *(const bf16x8*)(&smem[BBASE + row * 128 + ((kc * 64 + g * 16) ^ ((row & 7) << 4))]);
#pragma unroll
        for (int mt = 0; mt < 4; ++mt)
          acc[mt][nt] = MFMA16(af[mt], bf, acc[mt][nt]);
      }
    }
  }
  __syncthreads();

  // write C1 (bf16) into LDS: [pair][k=e*32+c]
  // swizzle: ^(pair&7)<<4 spreads phase-B reads; ^(e&6)<<3 spreads this write
#pragma unroll
  for (int mt = 0; mt < 4; ++mt) {
#pragma unroll
    for (int nt = 0; nt < 4; ++nt) {
      int il = wm * 2 + (mt >> 1);
      int jl = wn * 2 + (nt >> 1);
      int pair = il * 4 + jl;
      int c0 = (mt & 1) * 16 + g * 4;
      int e = (nt & 1) * 16 + l15;
      uint2 val;
      val.x = pack2bf(acc[mt][nt][0], acc[mt][nt][1]);
      val.y = pack2bf(acc[mt][nt][2], acc[mt][nt][3]);
      *(uint2*)(&smem[pair * 2048 +
                      ((e * 64 + c0 * 2) ^ ((pair & 7) << 4) ^ ((e & 6) << 3))]) = val;
    }
  }
  __syncthreads();

  // Phase B: each wave owns z-tile [wid*16,+16); A-frags = C1 rows (pairs)
  f32x4 acc2[2] = {zero4, zero4};
  const int z = wid * 16 + l15;
  const char* wrow = (const char*)wo_t + (size_t)z * 2048;
#pragma unroll 4
  for (int kc = 0; kc < 32; ++kc) {
    bf16x8 bfr = *(const bf16x8*)(wrow + kc * 64 + g * 16);
#pragma unroll
    for (int mt = 0; mt < 2; ++mt) {
      int pair = mt * 16 + l15;
      bf16x8 afr = *(const bf16x8*)(&smem[pair * 2048 +
                      ((kc * 64 + g * 16) ^ ((pair & 7) << 4) ^ ((kc & 6) << 3))]);
      acc2[mt] = MFMA16(afr, bfr, acc2[mt]);
    }
  }
  float bz = bo[z];
#pragma unroll
  for (int mt = 0; mt < 2; ++mt) {
#pragma unroll
    for (int j = 0; j < 4; ++j) {
      int pair = mt * 16 + g * 4 + j;
      int il = pair >> 2, jl = pair & 3;
      int ii = bi * 8 + il, jj = bj * 4 + jl;
      float dv = 1e-3f + norm[ii * NRES + jj];
      out[(size_t)(ii * NRES + jj) * CZ + z] = (acc2[mt][j] + bz) / dv;
    }
  }
}

// ---------------- launcher ----------------
extern "C" void kernel_launch(void* const* d_in, const int* in_sizes, int n_in,
                              void* d_out, int out_size, void* d_ws, size_t ws_size,
                              hipStream_t stream) {
  const float* m    = (const float*)d_in[0];
  const float* mask = (const float*)d_in[1];
  const float* ln_w = (const float*)d_in[2];
  const float* ln_b = (const float*)d_in[3];
  const float* w1   = (const float*)d_in[4];
  const float* b1   = (const float*)d_in[5];
  const float* w2   = (const float*)d_in[6];
  const float* b2   = (const float*)d_in[7];
  const float* wo   = (const float*)d_in[8];
  const float* bo   = (const float*)d_in[9];
  float* out = (float*)d_out;

  char* ws = (char*)d_ws;
  __bf16* a_t   = (__bf16*)(ws + WS_AT);
  __bf16* b_t   = (__bf16*)(ws + WS_BT);
  __bf16* wo_t  = (__bf16*)(ws + WS_WOT);
  __bf16* wpack = (__bf16*)(ws + WS_WPACK);
  float*  bpack = (float*)(ws + WS_BPACK);
  float*  normp = (float*)(ws + WS_NORM);

  hipLaunchKernelGGL(k_prep, dim3(960), dim3(256), 0, stream,
                     ln_w, ln_b, w1, b1, w2, b2, wo, mask,
                     wpack, bpack, wo_t, normp);
  hipLaunchKernelGGL(k_lnproj, dim3(1536), dim3(256), 0, stream,
                     m, mask, wpack, bpack, a_t, b_t);
  hipLaunchKernelGGL(k_main, dim3(4608), dim3(512), 0, stream,
                     a_t, b_t, wo_t, bo, normp, out);
}